// Round 3
// baseline (1088.660 us; speedup 1.0000x reference)
//
#include <hip/hip_runtime.h>
#include <hip/hip_bf16.h>
#include <cstdint>
#include <cstddef>

#define L      2048
#define IN_DIM 256
#define HID    13
#define G      52            // 4*HID
#define VOCAB  50257
#define PRED_N ((size_t)L * VOCAB)
#define L2E    1.4426950408889634f

static __device__ __forceinline__ float fexp2(float x) { return __builtin_amdgcn_exp2f(x); }
static __device__ __forceinline__ float frcp(float x) { return __builtin_amdgcn_rcpf(x); }
static __device__ __forceinline__ float sigm(float z) { return 1.f - frcp(fexp2(z * L2E) + 1.f); }
static __device__ __forceinline__ float tanh_(float z) { return 1.f - 2.f * frcp(fexp2(z * (2.f * L2E)) + 1.f); }
static __device__ __forceinline__ float bcast(float v, int l) {
    return __int_as_float(__builtin_amdgcn_readlane(__float_as_int(v), l));
}

// ---------------------------------------------------------------------------
// Kernel 1: embedding gather (-> d_out embs section, f32) + u0 = Wih0@emb + b0
// grid = L blocks, 128 threads
// ---------------------------------------------------------------------------
__global__ void k_emb_u0(const int* __restrict__ x, const float* __restrict__ embW,
                         const float* __restrict__ Wih0, const float* __restrict__ b0,
                         float* __restrict__ out_embs, float* __restrict__ u0)
{
    __shared__ float se[IN_DIM];
    int t = blockIdx.x;
    int tid = threadIdx.x;            // 128
    int row = x[t];
    float2 e = ((const float2*)(embW + (size_t)row * IN_DIM))[tid];
    se[2 * tid]     = e.x;
    se[2 * tid + 1] = e.y;
    ((float2*)(out_embs + (size_t)t * IN_DIM))[tid] = e;
    __syncthreads();
    if (tid < 2 * G) {
        int dir = tid / G, g = tid % G;
        float acc = b0[dir * G + g];
        const float* w = Wih0 + (size_t)(dir * G + g) * IN_DIM;
        #pragma unroll 8
        for (int k = 0; k < IN_DIM; ++k)
            acc = fmaf(w[k], se[k], acc);
        u0[(size_t)(dir * L + t) * G + g] = acc;
    }
}

// ---------------------------------------------------------------------------
// Kernel 2: decoder rows 1..L-1 (zero-state cells, parallel). dec[i][j], j<26
// ---------------------------------------------------------------------------
__global__ void k_rest(const int* __restrict__ x, const float* __restrict__ dWih,
                       const float* __restrict__ db, float* __restrict__ dec)
{
    int idx = blockIdx.x * blockDim.x + threadIdx.x;
    if (idx >= (L - 1) * 2 * HID) return;
    int i = idx / (2 * HID) + 1;
    int j = idx % (2 * HID);
    int dir = j / HID, jj = j % HID;
    float v = (float)x[i - 1];
    int base = dir * G;
    // c = 0 so the f-gate contributes nothing
    float zi = fmaf(dWih[base + jj],           v, db[base + jj]);
    float zg = fmaf(dWih[base + 2 * HID + jj], v, db[base + 2 * HID + jj]);
    float zo = fmaf(dWih[base + 3 * HID + jj], v, db[base + 3 * HID + jj]);
    float c2 = sigm(zi) * tanh_(zg);
    dec[(size_t)i * (2 * HID) + j] = sigm(zo) * tanh_(c2);
}

// ---------------------------------------------------------------------------
// Kernel 3/5: one LSTM direction per block (1 wave, 52 active lanes = gate rows).
// u layout: [dir][L][G] fp32 (bias folded). Deep register prefetch of u.
// dir 0 = forward, dir 1 = backward.
// ---------------------------------------------------------------------------
__global__ void __launch_bounds__(64) k_phase(const float* __restrict__ u,
                                              const float* __restrict__ Whh,
                                              float* __restrict__ out0,
                                              float* __restrict__ fin_h, float* __restrict__ fin_c,
                                              int chain_base, int do_out0)
{
    int dir  = blockIdx.x;
    int lane = threadIdx.x;
    int lg   = lane < G ? lane : G - 1;

    float whh[HID];
    #pragma unroll
    for (int k = 0; k < HID; ++k) whh[k] = Whh[(dir * G + lg) * HID + k];

    float m, kc;
    if (lane >= G)                              { m = 0.f;       kc = 0.f; }   // idle lanes
    else if (lane >= 2 * HID && lane < 3 * HID) { m = 2.f * L2E; kc = 2.f; }   // g-gate: tanh
    else                                        { m = L2E;       kc = 1.f; }   // i,f,o: sigmoid

    const float* ub = u + (size_t)dir * L * G + lg;
    int pstep = dir ? -1 : 1;
    int pos0  = dir ? (L - 1) : 0;

    float h = 0.f, c = 0.f;
    float cur[8], nxt[8];
    #pragma unroll
    for (int k = 0; k < 8; ++k) cur[k] = ub[(pos0 + k * pstep) * G];
    #pragma unroll
    for (int k = 0; k < 8; ++k) nxt[k] = cur[k];

    for (int tc = 0; tc < L; tc += 8) {
        if (tc + 8 < L) {
            int p = pos0 + (tc + 8) * pstep;
            #pragma unroll
            for (int k = 0; k < 8; ++k) nxt[k] = ub[(p + k * pstep) * G];
        }
        #pragma unroll
        for (int k = 0; k < 8; ++k) {
            float a0 = cur[k], a1 = 0.f;
            #pragma unroll
            for (int q = 0; q < HID; ++q) {
                float hq = bcast(h, q);
                if (q & 1) a1 = fmaf(whh[q], hq, a1);
                else       a0 = fmaf(whh[q], hq, a0);
            }
            float z   = a0 + a1;
            float act = fmaf(-kc, frcp(fexp2(m * z) + 1.f), 1.f);
            float sf  = __shfl(act, HID + lane);
            float tg  = __shfl(act, 2 * HID + lane);
            float so  = __shfl(act, 3 * HID + lane);
            float c2  = fmaf(sf, c, act * tg);
            float th  = tanh_(c2);
            h = so * th;
            c = c2;
            if (do_out0 && lane < HID)
                out0[(size_t)(pos0 + (tc + k) * pstep) * (2 * HID) + dir * HID + lane] = h;
        }
        #pragma unroll
        for (int k = 0; k < 8; ++k) cur[k] = nxt[k];
    }
    if (lane < HID) {
        fin_h[(chain_base + dir) * HID + lane] = h;
        fin_c[(chain_base + dir) * HID + lane] = c;
    }
}

// ---------------------------------------------------------------------------
// Kernel 4: u1 = Wih1 @ out0 + b1 for all t (parallel)
// ---------------------------------------------------------------------------
__global__ void k_u1(const float* __restrict__ out0, const float* __restrict__ Wih1,
                     const float* __restrict__ b1, float* __restrict__ u1)
{
    int idx = blockIdx.x * blockDim.x + threadIdx.x;
    if (idx >= L * 2 * G) return;
    int t = idx / (2 * G);
    int q = idx % (2 * G);
    int dir = q / G, g = q % G;
    float acc = b1[dir * G + g];
    const float* w = Wih1 + (size_t)(dir * G + g) * (2 * HID);
    const float* o = out0 + (size_t)t * (2 * HID);
    #pragma unroll
    for (int k = 0; k < 2 * HID; ++k)
        acc = fmaf(w[k], o[k], acc);
    u1[(size_t)(dir * L + t) * G + g] = acc;
}

// ---------------------------------------------------------------------------
// Kernel 6: projections + decoder step 0 (with state) -> dec[0][0:26]
// 1 block, 64 threads
// ---------------------------------------------------------------------------
__global__ void __launch_bounds__(64) k_final(const float* __restrict__ fin_h, const float* __restrict__ fin_c,
                                              const float* __restrict__ p1W, const float* __restrict__ p1b,
                                              const float* __restrict__ p2W, const float* __restrict__ p2b,
                                              const float* __restrict__ dWih, const float* __restrict__ dWhh,
                                              const float* __restrict__ db, float* __restrict__ dec)
{
    __shared__ float sh[2 * HID], sc[2 * HID], sz[G];
    int tid = threadIdx.x;
    if (tid < 4 * HID) {
        int r = tid < 2 * HID ? tid : tid - 2 * HID;
        const float* W   = tid < 2 * HID ? p1W : p2W;
        const float* src = tid < 2 * HID ? fin_h : fin_c;
        float acc = tid < 2 * HID ? p1b[r] : p2b[r];
        for (int k = 0; k < 4 * HID; ++k) acc = fmaf(W[r * 4 * HID + k], src[k], acc);
        if (tid < 2 * HID) sh[r] = acc; else sc[r] = acc;
    }
    __syncthreads();
    for (int dir = 0; dir < 2; ++dir) {
        if (tid < G) {
            float acc = db[dir * G + tid] - dWih[dir * G + tid];   // input = -1.0
            for (int k = 0; k < HID; ++k)
                acc = fmaf(dWhh[(dir * G + tid) * HID + k], sh[dir * HID + k], acc);
            sz[tid] = acc;
        }
        __syncthreads();
        if (tid < HID) {
            float si = sigm(sz[tid]);
            float sf = sigm(sz[HID + tid]);
            float tg = tanh_(sz[2 * HID + tid]);
            float so = sigm(sz[3 * HID + tid]);
            float c2 = fmaf(sf, sc[dir * HID + tid], si * tg);
            dec[dir * HID + tid] = so * tanh_(c2);
        }
        __syncthreads();
    }
}

// ---------------------------------------------------------------------------
// Kernel 7: preds = dec(2048x26) @ out_W^T(26x50257) + out_b   -> f32
// grid (ceil(V/512), 16), 256 threads; 2 n's per thread; 128 i-rows per block
// ---------------------------------------------------------------------------
__global__ void __launch_bounds__(256) k_out(const float* __restrict__ dec,
                                             const float* __restrict__ outW,
                                             const float* __restrict__ outb,
                                             float* __restrict__ preds)
{
    __shared__ float sd[128][28];
    int tid = threadIdx.x;
    int nbase = blockIdx.x * 512;
    int i0 = blockIdx.y * 128;
    for (int li = tid; li < 128 * 26; li += 256) {
        int r = li / 26, cc = li % 26;
        sd[r][cc] = dec[(size_t)(i0 + r) * 26 + cc];
    }
    __syncthreads();

    int n0 = nbase + tid, n1 = nbase + 256 + tid;
    bool a0 = n0 < VOCAB, a1 = n1 < VOCAB;
    float w0[26], w1[26];
    float b0v = 0.f, b1v = 0.f;
    #pragma unroll
    for (int k = 0; k < 26; ++k) { w0[k] = 0.f; w1[k] = 0.f; }
    if (a0) {
        const float* w = outW + (size_t)n0 * 26;
        #pragma unroll
        for (int k = 0; k < 26; ++k) w0[k] = w[k];
        b0v = outb[n0];
    }
    if (a1) {
        const float* w = outW + (size_t)n1 * 26;
        #pragma unroll
        for (int k = 0; k < 26; ++k) w1[k] = w[k];
        b1v = outb[n1];
    }
    for (int i = 0; i < 128; ++i) {
        float acc0 = b0v, acc1 = b1v;
        const float* dr = sd[i];
        #pragma unroll
        for (int k = 0; k < 26; ++k) {
            float d = dr[k];
            acc0 = fmaf(d, w0[k], acc0);
            acc1 = fmaf(d, w1[k], acc1);
        }
        size_t rb = (size_t)(i0 + i) * VOCAB;
        if (a0) preds[rb + n0] = acc0;
        if (a1) preds[rb + n1] = acc1;
    }
}

// ---------------------------------------------------------------------------
extern "C" void kernel_launch(void* const* d_in, const int* in_sizes, int n_in,
                              void* d_out, int out_size, void* d_ws, size_t ws_size,
                              hipStream_t stream)
{
    (void)in_sizes; (void)n_in; (void)out_size; (void)ws_size;

    const int*   x     = (const int*)d_in[0];
    const float* embW  = (const float*)d_in[1];
    const float* eWih0 = (const float*)d_in[2];
    const float* eWhh0 = (const float*)d_in[3];
    const float* eb0   = (const float*)d_in[4];
    const float* eWih1 = (const float*)d_in[5];
    const float* eWhh1 = (const float*)d_in[6];
    const float* eb1   = (const float*)d_in[7];
    const float* p1W   = (const float*)d_in[8];
    const float* p1b   = (const float*)d_in[9];
    const float* p2W   = (const float*)d_in[10];
    const float* p2b   = (const float*)d_in[11];
    const float* dWih  = (const float*)d_in[12];
    const float* dWhh  = (const float*)d_in[13];
    const float* db    = (const float*)d_in[14];
    const float* outW  = (const float*)d_in[15];
    const float* outb  = (const float*)d_in[16];

    float* ws    = (float*)d_ws;
    float* u0    = ws;                    // 2*L*G
    float* u1    = u0 + 2 * L * G;        // 2*L*G
    float* out0  = u1 + 2 * L * G;        // L*26
    float* dec   = out0 + L * 2 * HID;    // L*26
    float* fin_h = dec + L * 2 * HID;     // 52
    float* fin_c = fin_h + G;             // 52

    float* preds    = (float*)d_out;
    float* out_embs = preds + PRED_N;

    hipLaunchKernelGGL(k_emb_u0, dim3(L), dim3(128), 0, stream,
                       x, embW, eWih0, eb0, out_embs, u0);

    int restN = (L - 1) * 2 * HID;
    hipLaunchKernelGGL(k_rest, dim3((restN + 255) / 256), dim3(256), 0, stream, x, dWih, db, dec);

    hipLaunchKernelGGL(k_phase, dim3(2), dim3(64), 0, stream,
                       u0, eWhh0, out0, fin_h, fin_c, 0, 1);

    int u1N = L * 2 * G;
    hipLaunchKernelGGL(k_u1, dim3((u1N + 255) / 256), dim3(256), 0, stream,
                       out0, eWih1, eb1, u1);

    hipLaunchKernelGGL(k_phase, dim3(2), dim3(64), 0, stream,
                       u1, eWhh1, (float*)nullptr, fin_h, fin_c, 2, 0);

    hipLaunchKernelGGL(k_final, dim3(1), dim3(64), 0, stream,
                       fin_h, fin_c, p1W, p1b, p2W, p2b, dWih, dWhh, db, dec);

    hipLaunchKernelGGL(k_out, dim3((VOCAB + 511) / 512, L / 128), dim3(256), 0, stream,
                       dec, outW, outb, preds);
}

// Round 4
// 694.847 us; speedup vs baseline: 1.5668x; 1.5668x over previous
//
#include <hip/hip_runtime.h>
#include <hip/hip_bf16.h>
#include <cstdint>
#include <cstddef>

#define L      2048
#define IN_DIM 256
#define HID    13
#define G      52            // 4*HID
#define VOCAB  50257
#define PRED_N ((size_t)L * VOCAB)
#define L2E    1.4426950408889634f
#define NTX    99            // x-tiles of 512 cols (99*512 >= 50257)
#define NTY    16            // y-tiles of 128 rows
#define NTILE  (NTX * NTY)   // 1584
#define TILE_SPLIT (NTILE / 2)

static __device__ __forceinline__ float fexp2(float x) { return __builtin_amdgcn_exp2f(x); }
static __device__ __forceinline__ float frcp(float x) { return __builtin_amdgcn_rcpf(x); }
static __device__ __forceinline__ float sigm(float z) { return 1.f - frcp(fexp2(z * L2E) + 1.f); }
static __device__ __forceinline__ float tanh_(float z) { return 1.f - 2.f * frcp(fexp2(z * (2.f * L2E)) + 1.f); }
static __device__ __forceinline__ float bcast(float v, int l) {
    return __int_as_float(__builtin_amdgcn_readlane(__float_as_int(v), l));
}

// ---------------------------------------------------------------------------
// Kernel 1: embedding gather (-> d_out embs section, f32) + u0 = msc*(Wih0@emb+b0)
// padded layout [dir][L][64]; grid = L blocks, 128 threads
// ---------------------------------------------------------------------------
__global__ void k_emb_u0(const int* __restrict__ x, const float* __restrict__ embW,
                         const float* __restrict__ Wih0, const float* __restrict__ b0,
                         float* __restrict__ out_embs, float* __restrict__ u0)
{
    __shared__ float se[IN_DIM];
    int t = blockIdx.x;
    int tid = threadIdx.x;            // 128
    int rowx = x[t];
    float2 e = ((const float2*)(embW + (size_t)rowx * IN_DIM))[tid];
    se[2 * tid]     = e.x;
    se[2 * tid + 1] = e.y;
    ((float2*)(out_embs + (size_t)t * IN_DIM))[tid] = e;
    __syncthreads();
    if (tid < 2 * G) {
        int dirg = tid / G, g = tid % G;
        int gate = g / HID, row = g % HID;
        float msc = (gate == 2) ? 2.f * L2E : L2E;
        float acc = b0[dirg * G + g];
        const float* w = Wih0 + (size_t)(dirg * G + g) * IN_DIM;
        #pragma unroll 8
        for (int k = 0; k < IN_DIM; ++k)
            acc = fmaf(w[k], se[k], acc);
        u0[((size_t)dirg * L + t) * 64 + gate * 16 + row] = msc * acc;
    } else {
        int p = tid - 2 * G;          // 0..23 -> zero the 2*12 pad slots
        int dirp = p / 12, pp = p % 12;
        int gate = pp / 3, row = HID + pp % 3;
        u0[((size_t)dirp * L + t) * 64 + gate * 16 + row] = 0.f;
    }
}

// ---------------------------------------------------------------------------
// Kernel 2: decoder rows 1..L-1 (zero-state cells, parallel). dec[i][j], j<26
// ---------------------------------------------------------------------------
__global__ void k_rest(const int* __restrict__ x, const float* __restrict__ dWih,
                       const float* __restrict__ db, float* __restrict__ dec)
{
    int idx = blockIdx.x * blockDim.x + threadIdx.x;
    if (idx >= (L - 1) * 2 * HID) return;
    int i = idx / (2 * HID) + 1;
    int j = idx % (2 * HID);
    int dir = j / HID, jj = j % HID;
    float v = (float)x[i - 1];
    int base = dir * G;
    float zi = fmaf(dWih[base + jj],           v, db[base + jj]);
    float zg = fmaf(dWih[base + 2 * HID + jj], v, db[base + 2 * HID + jj]);
    float zo = fmaf(dWih[base + 3 * HID + jj], v, db[base + 3 * HID + jj]);
    float c2 = sigm(zi) * tanh_(zg);
    dec[(size_t)i * (2 * HID) + j] = sigm(zo) * tanh_(c2);
}

// ---------------------------------------------------------------------------
// Kernel 3/5: blocks 0,1 = one LSTM direction each (1 wave, padded gate layout,
// permlane exchanges). blocks >=2 = output-GEMM tiles (rows 1..L-1), hidden
// under the recurrence latency.
// ---------------------------------------------------------------------------
__global__ void __launch_bounds__(256) k_phase(
    const float* __restrict__ u, const float* __restrict__ Whh,
    float* __restrict__ out0, float* __restrict__ finh, float* __restrict__ finc,
    int chain_base, int do_out0,
    const float* __restrict__ dec, const float* __restrict__ outW,
    const float* __restrict__ outb, float* __restrict__ preds, int tile_base)
{
    __shared__ float sd[128][28];
    int bid = blockIdx.x;
    int tid = threadIdx.x;
    if (bid >= 2) {
        // ---- output-GEMM tile ----
        int tile = bid - 2 + tile_base;
        int ix = tile % NTX, iy = tile / NTX;
        int nbase = ix * 512, i0 = iy * 128;
        for (int li = tid; li < 128 * 26; li += 256) {
            int r = li / 26, cc = li % 26;
            sd[r][cc] = dec[(size_t)(i0 + r) * 26 + cc];
        }
        __syncthreads();
        int n0 = nbase + tid, n1 = nbase + 256 + tid;
        bool a0 = n0 < VOCAB, a1 = n1 < VOCAB;
        float w0[26], w1[26], b0v = 0.f, b1v = 0.f;
        #pragma unroll
        for (int k = 0; k < 26; ++k) { w0[k] = 0.f; w1[k] = 0.f; }
        if (a0) { const float* w = outW + (size_t)n0 * 26;
            #pragma unroll
            for (int k = 0; k < 26; ++k) w0[k] = w[k];
            b0v = outb[n0]; }
        if (a1) { const float* w = outW + (size_t)n1 * 26;
            #pragma unroll
            for (int k = 0; k < 26; ++k) w1[k] = w[k];
            b1v = outb[n1]; }
        for (int i = 0; i < 128; ++i) {
            int grow = i0 + i;
            float acc0 = b0v, acc1 = b1v;
            const float* dr = sd[i];
            #pragma unroll
            for (int k = 0; k < 26; ++k) {
                float d = dr[k];
                acc0 = fmaf(d, w0[k], acc0);
                acc1 = fmaf(d, w1[k], acc1);
            }
            if (grow != 0) {                     // row 0 written later by k_row0
                size_t rb = (size_t)grow * VOCAB;
                if (a0) preds[rb + n0] = acc0;
                if (a1) preds[rb + n1] = acc1;
            }
        }
        return;
    }
    if (tid >= 64) return;
    // ---- recurrence (wave 0 of blocks 0,1) ----
    int dir = bid, lane = tid;
    int row = lane & 15, gate = lane >> 4;
    int rsrc = gate * HID + (row < HID ? row : HID - 1);   // clamp pad rows
    float msc = (gate == 2) ? 2.f * L2E : L2E;
    float kcv = (gate == 2) ? 2.f : 1.f;
    float whh[HID];
    #pragma unroll
    for (int k = 0; k < HID; ++k) whh[k] = msc * Whh[(dir * G + rsrc) * HID + k];

    // runtime detection of permlane swap operand direction (wave-uniform)
    float ta = (float)lane, tb = (float)lane;
    asm("s_nop 1\n\tv_permlane16_swap_b32 %0, %1" : "+v"(ta), "+v"(tb));
    bool selA16 = __builtin_amdgcn_readfirstlane(__float_as_int(ta)) == __float_as_int(16.0f);
    float tc32a = (float)lane, tc32b = (float)lane;
    asm("s_nop 1\n\tv_permlane32_swap_b32 %0, %1" : "+v"(tc32a), "+v"(tc32b));
    bool selA32 = __builtin_amdgcn_readfirstlane(__float_as_int(tc32a)) == __float_as_int(32.0f);

    const float* ub = u + (size_t)dir * L * 64 + lane;
    int pstep = dir ? -64 : 64;
    int poff  = dir ? (L - 1) * 64 : 0;
    float h = 0.f, c = 0.f;
    float cur[8], nxt[8];
    #pragma unroll
    for (int k = 0; k < 8; ++k) cur[k] = ub[poff + k * pstep];
    #pragma unroll
    for (int k = 0; k < 8; ++k) nxt[k] = cur[k];

    for (int tcb = 0; tcb < L; tcb += 8) {
        if (tcb + 8 < L) {
            int p = poff + (tcb + 8) * pstep;
            #pragma unroll
            for (int k = 0; k < 8; ++k) nxt[k] = ub[p + k * pstep];
        }
        #pragma unroll
        for (int k = 0; k < 8; ++k) {
            float h0 = bcast(h, 0), h1 = bcast(h, 1), h2 = bcast(h, 2), h3 = bcast(h, 3);
            float h4 = bcast(h, 4), h5 = bcast(h, 5), h6 = bcast(h, 6), h7 = bcast(h, 7);
            float h8 = bcast(h, 8), h9 = bcast(h, 9), h10 = bcast(h, 10), h11 = bcast(h, 11);
            float h12 = bcast(h, 12);
            float A = fmaf(whh[0], h0, cur[k]);
            float B = whh[1] * h1;
            float C = whh[2] * h2;
            float D = whh[3] * h3;
            A = fmaf(whh[4], h4, A);   B = fmaf(whh[5], h5, B);
            C = fmaf(whh[6], h6, C);   D = fmaf(whh[7], h7, D);
            A = fmaf(whh[8], h8, A);   B = fmaf(whh[9], h9, B);
            C = fmaf(whh[10], h10, C); D = fmaf(whh[11], h11, D);
            A = fmaf(whh[12], h12, A);
            float z = (A + B) + (C + D);              // pre-scaled by msc
            float rc = frcp(fexp2(z) + 1.f);
            float act = fmaf(-kcv, rc, 1.f);          // sigmoid or tanh per gate
            float pa = act, pb = act;
            asm("s_nop 1\n\tv_permlane16_swap_b32 %0, %1" : "+v"(pa), "+v"(pb));
            float sf = selA16 ? pa : pb;              // act[lane+16] (f-gate)
            float qa = act, qb = act;
            asm("s_nop 1\n\tv_permlane32_swap_b32 %0, %1" : "+v"(qa), "+v"(qb));
            float tg = selA32 ? qa : qb;              // act[lane+32] (g-gate)
            float ra = tg, rb = tg;
            asm("s_nop 1\n\tv_permlane16_swap_b32 %0, %1" : "+v"(ra), "+v"(rb));
            float so = selA16 ? ra : rb;              // act[lane+48] (o-gate)
            float c2 = fmaf(sf, c, act * tg);
            float th = fmaf(-2.f, frcp(fexp2(c2 * (2.f * L2E)) + 1.f), 1.f);
            h = so * th;
            c = c2;
            if (do_out0 && lane < HID)
                out0[(size_t)((poff + (tcb + k) * pstep) >> 6) * (2 * HID) + dir * HID + lane] = h;
        }
        #pragma unroll
        for (int k = 0; k < 8; ++k) cur[k] = nxt[k];
    }
    if (lane < HID) {
        finh[(chain_base + dir) * HID + lane] = h;
        finc[(chain_base + dir) * HID + lane] = c;
    }
}

// ---------------------------------------------------------------------------
// Kernel 4: u1 = msc*(Wih1 @ out0 + b1), padded [dir][L][64]
// ---------------------------------------------------------------------------
__global__ void k_u1(const float* __restrict__ out0, const float* __restrict__ Wih1,
                     const float* __restrict__ b1, float* __restrict__ u1)
{
    int idx = blockIdx.x * blockDim.x + threadIdx.x;
    if (idx >= L * 2 * 64) return;
    int t    = idx >> 7;
    int remv = idx & 127;
    int d1   = remv >> 6;
    int lane = remv & 63;
    int gate = lane >> 4, row = lane & 15;
    size_t oidx = ((size_t)d1 * L + t) * 64 + lane;
    if (row >= HID) { u1[oidx] = 0.f; return; }
    int g = gate * HID + row;
    float msc = (gate == 2) ? 2.f * L2E : L2E;
    float acc = b1[d1 * G + g];
    const float* w = Wih1 + (size_t)(d1 * G + g) * (2 * HID);
    const float* o = out0 + (size_t)t * (2 * HID);
    #pragma unroll
    for (int k = 0; k < 2 * HID; ++k)
        acc = fmaf(w[k], o[k], acc);
    u1[oidx] = msc * acc;
}

// ---------------------------------------------------------------------------
// Kernel 6: projections + decoder step 0 (with state) -> dec[0][0:26]
// ---------------------------------------------------------------------------
__global__ void __launch_bounds__(64) k_final(const float* __restrict__ fin_h, const float* __restrict__ fin_c,
                                              const float* __restrict__ p1W, const float* __restrict__ p1b,
                                              const float* __restrict__ p2W, const float* __restrict__ p2b,
                                              const float* __restrict__ dWih, const float* __restrict__ dWhh,
                                              const float* __restrict__ db, float* __restrict__ dec)
{
    __shared__ float sh[2 * HID], sc[2 * HID], sz[G];
    int tid = threadIdx.x;
    if (tid < 4 * HID) {
        int r = tid < 2 * HID ? tid : tid - 2 * HID;
        const float* W   = tid < 2 * HID ? p1W : p2W;
        const float* src = tid < 2 * HID ? fin_h : fin_c;
        float acc = tid < 2 * HID ? p1b[r] : p2b[r];
        for (int k = 0; k < 4 * HID; ++k) acc = fmaf(W[r * 4 * HID + k], src[k], acc);
        if (tid < 2 * HID) sh[r] = acc; else sc[r] = acc;
    }
    __syncthreads();
    for (int dir = 0; dir < 2; ++dir) {
        if (tid < G) {
            float acc = db[dir * G + tid] - dWih[dir * G + tid];   // input = -1.0
            for (int k = 0; k < HID; ++k)
                acc = fmaf(dWhh[(dir * G + tid) * HID + k], sh[dir * HID + k], acc);
            sz[tid] = acc;
        }
        __syncthreads();
        if (tid < HID) {
            float si = sigm(sz[tid]);
            float sf = sigm(sz[HID + tid]);
            float tg = tanh_(sz[2 * HID + tid]);
            float so = sigm(sz[3 * HID + tid]);
            float c2 = fmaf(sf, sc[dir * HID + tid], si * tg);
            dec[dir * HID + tid] = so * tanh_(c2);
        }
        __syncthreads();
    }
}

// ---------------------------------------------------------------------------
// Kernel 7: preds row 0 only
// ---------------------------------------------------------------------------
__global__ void k_row0(const float* __restrict__ dec, const float* __restrict__ outW,
                       const float* __restrict__ outb, float* __restrict__ preds)
{
    int n = blockIdx.x * blockDim.x + threadIdx.x;
    if (n >= VOCAB) return;
    float acc = outb[n];
    const float* w = outW + (size_t)n * 26;
    #pragma unroll
    for (int k = 0; k < 26; ++k) acc = fmaf(w[k], dec[k], acc);
    preds[n] = acc;
}

// ---------------------------------------------------------------------------
extern "C" void kernel_launch(void* const* d_in, const int* in_sizes, int n_in,
                              void* d_out, int out_size, void* d_ws, size_t ws_size,
                              hipStream_t stream)
{
    (void)in_sizes; (void)n_in; (void)out_size; (void)ws_size;

    const int*   x     = (const int*)d_in[0];
    const float* embW  = (const float*)d_in[1];
    const float* eWih0 = (const float*)d_in[2];
    const float* eWhh0 = (const float*)d_in[3];
    const float* eb0   = (const float*)d_in[4];
    const float* eWih1 = (const float*)d_in[5];
    const float* eWhh1 = (const float*)d_in[6];
    const float* eb1   = (const float*)d_in[7];
    const float* p1W   = (const float*)d_in[8];
    const float* p1b   = (const float*)d_in[9];
    const float* p2W   = (const float*)d_in[10];
    const float* p2b   = (const float*)d_in[11];
    const float* dWih  = (const float*)d_in[12];
    const float* dWhh  = (const float*)d_in[13];
    const float* db    = (const float*)d_in[14];
    const float* outW  = (const float*)d_in[15];
    const float* outb  = (const float*)d_in[16];

    float* ws    = (float*)d_ws;
    float* u0    = ws;                       // 2*L*64
    float* u1    = u0 + 2 * L * 64;          // 2*L*64
    float* out0  = u1 + 2 * L * 64;          // L*26
    float* dec   = out0 + L * 2 * HID;       // L*26
    float* fin_h = dec + L * 2 * HID;        // 52
    float* fin_c = fin_h + G;                // 52

    float* preds    = (float*)d_out;
    float* out_embs = preds + PRED_N;

    hipLaunchKernelGGL(k_emb_u0, dim3(L), dim3(128), 0, stream,
                       x, embW, eWih0, eb0, out_embs, u0);

    int restN = (L - 1) * 2 * HID;
    hipLaunchKernelGGL(k_rest, dim3((restN + 255) / 256), dim3(256), 0, stream, x, dWih, db, dec);

    hipLaunchKernelGGL(k_phase, dim3(2 + TILE_SPLIT), dim3(256), 0, stream,
                       u0, eWhh0, out0, fin_h, fin_c, 0, 1,
                       dec, outW, outb, preds, 0);

    hipLaunchKernelGGL(k_u1, dim3((L * 2 * 64 + 255) / 256), dim3(256), 0, stream,
                       out0, eWih1, eb1, u1);

    hipLaunchKernelGGL(k_phase, dim3(2 + (NTILE - TILE_SPLIT)), dim3(256), 0, stream,
                       u1, eWhh1, (float*)nullptr, fin_h, fin_c, 2, 0,
                       dec, outW, outb, preds, TILE_SPLIT);

    hipLaunchKernelGGL(k_final, dim3(1), dim3(64), 0, stream,
                       fin_h, fin_c, p1W, p1b, p2W, p2b, dWih, dWhh, db, dec);

    hipLaunchKernelGGL(k_row0, dim3((VOCAB + 255) / 256), dim3(256), 0, stream,
                       dec, outW, outb, preds);
}